// Round 4
// baseline (490133.008 us; speedup 1.0000x reference)
//
#include <hip/hip_runtime.h>
#include <hip/hip_bf16.h>

#define BB 64          // batch
#define TENC 512
#define ENCD 512
#define TDEC 600
#define MEL 80
#define RNN 1024
#define ATT 128
#define CC 32
#define KSZ 31
#define PADC 15
#define PRE 256

// ---- all scratch in __device__ globals: d_ws is NOT used at all ----
__device__ float g_dall[(size_t)TDEC * BB * PRE];   // prenet out, 39.3 MB
__device__ float g_pm[(size_t)BB * TENC * ATT];     // processed_memory, 16.8 MB
__device__ float g_h1[2][BB * RNN];
__device__ float g_c1[BB * RNN];
__device__ float g_h2[2][BB * RNN];
__device__ float g_c2[BB * RNN];
__device__ float g_ctx[BB * ENCD];
__device__ float g_cum[BB * TENC];
__device__ float g_ebuf[BB * TENC];

__device__ __forceinline__ float fast_tanh(float x) {
  x = fminf(15.f, fmaxf(-15.f, x));
  float e = __expf(2.f * x);
  return __fdividef(e - 1.f, e + 1.f);
}
__device__ __forceinline__ float fast_sig(float x) {
  x = fminf(30.f, fmaxf(-30.f, x));
  return __fdividef(1.f, 1.f + __expf(-x));
}

// ---------------- init: zero recurrent state (every call) ----------------
__global__ __launch_bounds__(256) void k_init() {
  int i = blockIdx.x * 256 + threadIdx.x;   // grid 512 -> i < 131072
  if (i < 2 * BB * RNN) {
    ((float*)g_h1)[i] = 0.f;
    ((float*)g_h2)[i] = 0.f;
  }
  if (i < BB * RNN) {
    g_c1[i] = 0.f;
    g_c2[i] = 0.f;
  }
  if (i < BB * ENCD) g_ctx[i] = 0.f;
  if (i < BB * TENC) g_cum[i] = 0.f;
}

// ---------------- prenet (all 600 steps, once) ----------------
// grid: 64 b * 75 tchunks, 256 threads. g_dall[(t*64+b)*256 + i]
__global__ __launch_bounds__(256) void k_prenet(
    const float* __restrict__ DT, const float* __restrict__ W0,
    const float* __restrict__ W1) {
  int bid = blockIdx.x;
  int b = bid / 75, ch = bid % 75, t0 = ch * 8;
  int tid = threadIdx.x;
  __shared__ float xl[8 * 80];
  __shared__ float hl[8 * 256];
  for (int i = tid; i < 8 * 80; i += 256) {
    int tt = i / 80, m = i % 80, t = t0 + tt;
    xl[i] = (t == 0) ? 0.f : DT[(size_t)b * (MEL * TDEC) + m * TDEC + (t - 1)];
  }
  __syncthreads();
  {
    float acc[8] = {0, 0, 0, 0, 0, 0, 0, 0};
    for (int m = 0; m < 80; ++m) {
      float w = W0[m * 256 + tid];
#pragma unroll
      for (int tt = 0; tt < 8; ++tt) acc[tt] += xl[tt * 80 + m] * w;
    }
#pragma unroll
    for (int tt = 0; tt < 8; ++tt) hl[tt * 256 + tid] = fmaxf(acc[tt], 0.f);
  }
  __syncthreads();
  {
    float acc[8] = {0, 0, 0, 0, 0, 0, 0, 0};
    for (int j = 0; j < 256; ++j) {
      float w = W1[j * 256 + tid];
#pragma unroll
      for (int tt = 0; tt < 8; ++tt) acc[tt] += hl[tt * 256 + j] * w;
    }
#pragma unroll
    for (int tt = 0; tt < 8; ++tt)
      g_dall[((size_t)(t0 + tt) * BB + b) * 256 + tid] = fmaxf(acc[tt], 0.f);
  }
}

// ---------------- processed_memory (once) ----------------
// grid: 64 b * 64 tchunks, 128 threads. g_pm[(b*512+t)*128 + a]
__global__ __launch_bounds__(128) void k_pm(
    const float* __restrict__ mem, const float* __restrict__ mW) {
  int bid = blockIdx.x;
  int b = bid >> 6, ch = bid & 63, t0 = ch * 8;
  int tid = threadIdx.x;
  __shared__ float ml[8 * 512];
  for (int i = tid; i < 8 * 512; i += 128) {
    int tt = i >> 9, d = i & 511;
    ml[i] = mem[((size_t)b * TENC + t0 + tt) * ENCD + d];
  }
  __syncthreads();
  float acc[8] = {0, 0, 0, 0, 0, 0, 0, 0};
  for (int d = 0; d < 512; ++d) {
    float w = mW[d * 128 + tid];
#pragma unroll
    for (int tt = 0; tt < 8; ++tt) acc[tt] += ml[tt * 512 + d] * w;
  }
#pragma unroll
  for (int tt = 0; tt < 8; ++tt)
    g_pm[((size_t)b * TENC + t0 + tt) * 128 + tid] = acc[tt];
}

// ---------------- fused gates GEMM + LSTM pointwise ----------------
// PHASE 1: A = [dall_t(256) | ctx(512) | h1_prev(1024)], W = Wih1/Whh1
// PHASE 2: A = [h1_new(1024) | ctx(512) | h2_prev(1024)], W = Wih2/Whh2
// grid 256 WGs (hcols [wg*4,wg*4+4)), 256 threads.
template <int PHASE>
__global__ __launch_bounds__(256) void k_gates_lstm(
    int t, int pp, const float* __restrict__ Wih, const float* __restrict__ Whh,
    const float* __restrict__ bih, const float* __restrict__ bhh) {
  __shared__ float Al[64 * 68];
  __shared__ float Wl[64 * 16];
  const int tid = threadIdx.x;
  const int wg = blockIdx.x;
  const int b = tid >> 2;
  const int h = tid & 3;
  const int hn = 1 - pp;
  const int K = (PHASE == 1) ? 1792 : 2560;
  const int Kih = (PHASE == 1) ? 768 : 1536;
  float* __restrict__ c_st = (PHASE == 1) ? g_c1 : g_c2;
  float* __restrict__ h_out = (PHASE == 1) ? g_h1[hn] : g_h2[hn];
  float acc0 = 0, acc1 = 0, acc2 = 0, acc3 = 0;
  for (int kb = 0; kb < K; kb += 64) {
#pragma unroll
    for (int i = 0; i < 16; ++i) {
      int e = i * 256 + tid;
      int bb = e >> 6, kk = e & 63;
      int kg = kb + kk;
      float v;
      if (PHASE == 1) {
        if (kg < 256)
          v = g_dall[(size_t)t * BB * PRE + bb * 256 + kg];
        else if (kg < 768)
          v = g_ctx[bb * ENCD + (kg - 256)];
        else
          v = g_h1[pp][bb * RNN + (kg - 768)];
      } else {
        if (kg < 1024)
          v = g_h1[hn][bb * RNN + kg];
        else if (kg < 1536)
          v = g_ctx[bb * ENCD + (kg - 1024)];
        else
          v = g_h2[pp][bb * RNN + (kg - 1536)];
      }
      Al[bb * 68 + kk] = v;
    }
#pragma unroll
    for (int i = 0; i < 4; ++i) {
      int e = i * 256 + tid;
      int kk = e >> 4, cc = e & 15;
      int col = (cc >> 2) * 1024 + wg * 4 + (cc & 3);
      int kg = kb + kk;
      float w = (kg < Kih) ? Wih[(size_t)kg * 4096 + col]
                           : Whh[(size_t)(kg - Kih) * 4096 + col];
      Wl[kk * 16 + cc] = w;
    }
    __syncthreads();
#pragma unroll
    for (int kk = 0; kk < 64; ++kk) {
      float a = Al[b * 68 + kk];
      acc0 += a * Wl[kk * 16 + h];
      acc1 += a * Wl[kk * 16 + 4 + h];
      acc2 += a * Wl[kk * 16 + 8 + h];
      acc3 += a * Wl[kk * 16 + 12 + h];
    }
    __syncthreads();
  }
  int colh = wg * 4 + h;
  float gi = acc0 + bih[colh] + bhh[colh];
  float gf = acc1 + bih[1024 + colh] + bhh[1024 + colh];
  float gg = acc2 + bih[2048 + colh] + bhh[2048 + colh];
  float go = acc3 + bih[3072 + colh] + bhh[3072 + colh];
  float c_old = c_st[b * RNN + colh];
  float cn = fast_sig(gf) * c_old + fast_sig(gi) * fast_tanh(gg);
  c_st[b * RNN + colh] = cn;
  h_out[b * RNN + colh] = fast_sig(go) * fast_tanh(cn);
}

// ---------------- attention energies ----------------
// grid 128 (b*2 halves), 256 threads (one t each). reads h1_new = g_h1[1-pp]
__global__ __launch_bounds__(256) void k_energies(
    int pp, const float* __restrict__ qW, const float* __restrict__ convW,
    const float* __restrict__ locW, const float* __restrict__ wW,
    const float* __restrict__ wb, const int* __restrict__ mlen) {
  const int b = blockIdx.x >> 1;
  const int t0 = (blockIdx.x & 1) * 256;
  const int tid = threadIdx.x;
  const float* __restrict__ h1 = g_h1[1 - pp];
  __shared__ float cumext[TENC + 2 * PADC];
  __shared__ float h1l[RNN];
  __shared__ float pql[ATT];
  __shared__ float cWl[CC * KSZ];
  __shared__ float lWl[CC * ATT];
  __shared__ float wl[ATT];
  for (int i = tid; i < TENC; i += 256) cumext[PADC + i] = g_cum[b * TENC + i];
  if (tid < PADC) { cumext[tid] = 0.f; cumext[TENC + PADC + tid] = 0.f; }
  for (int i = tid; i < RNN; i += 256) h1l[i] = h1[b * RNN + i];
  for (int i = tid; i < CC * KSZ; i += 256) cWl[i] = convW[i];
  for (int i = tid; i < CC * ATT; i += 256) lWl[i] = locW[i];
  if (tid < ATT) wl[tid] = wW[tid];
  __syncthreads();
  if (tid < ATT) {
    float s = 0.f;
    for (int k = 0; k < RNN; ++k) s += h1l[k] * qW[k * ATT + tid];
    pql[tid] = s;
  }
  __syncthreads();
  const int t = t0 + tid;
  float win[KSZ];
#pragma unroll
  for (int k = 0; k < KSZ; ++k) win[k] = cumext[t0 + tid + k];
  float lc[CC];
#pragma unroll
  for (int c = 0; c < CC; ++c) {
    float s = 0.f;
#pragma unroll
    for (int k = 0; k < KSZ; ++k) s += win[k] * cWl[c * KSZ + k];
    lc[c] = s;
  }
  const float* pmrow = g_pm + ((size_t)b * TENC + t) * ATT;
  float e = 0.f;
  for (int a = 0; a < ATT; ++a) {
    float v = pql[a] + pmrow[a];
#pragma unroll
    for (int c = 0; c < CC; ++c) v += lc[c] * lWl[c * ATT + a];
    e += wl[a] * fast_tanh(v);
  }
  int len = mlen[b];
  g_ebuf[b * TENC + t] = (t >= len) ? -1e9f : (e + wb[0]);
}

// ---------------- softmax + ctx + cum + alignment out ----------------
// grid 64 (b), 256 threads
__global__ __launch_bounds__(256) void k_softmax_ctx(
    const float* __restrict__ memory, float* __restrict__ out_al, int t_step) {
  const int b = blockIdx.x;
  const int tid = threadIdx.x;
  __shared__ float pl[TENC];
  __shared__ float rmax[4], rsum[4];
  float e0 = g_ebuf[b * TENC + tid], e1 = g_ebuf[b * TENC + 256 + tid];
  float m = fmaxf(e0, e1);
#pragma unroll
  for (int o = 32; o > 0; o >>= 1) m = fmaxf(m, __shfl_xor(m, o, 64));
  if ((tid & 63) == 0) rmax[tid >> 6] = m;
  __syncthreads();
  float M = fmaxf(fmaxf(rmax[0], rmax[1]), fmaxf(rmax[2], rmax[3]));
  float p0 = __expf(e0 - M), p1 = __expf(e1 - M);
  pl[tid] = p0;
  pl[tid + 256] = p1;
  float s = p0 + p1;
#pragma unroll
  for (int o = 32; o > 0; o >>= 1) s += __shfl_xor(s, o, 64);
  if ((tid & 63) == 0) rsum[tid >> 6] = s;
  __syncthreads();
  float S = rsum[0] + rsum[1] + rsum[2] + rsum[3];
  float invS = __fdividef(1.f, S);
  for (int i = tid; i < TENC; i += 256) {
    float av = pl[i] * invS;
    out_al[(size_t)b * (TDEC * TENC) + (size_t)t_step * TENC + i] = av;
    g_cum[b * TENC + i] += av;
  }
  float a0 = 0.f, a1 = 0.f;
  const float* mb = memory + (size_t)b * TENC * ENCD;
  for (int tt = 0; tt < TENC; ++tt) {
    float av = pl[tt];
    a0 += av * mb[(size_t)tt * ENCD + tid];
    a1 += av * mb[(size_t)tt * ENCD + 256 + tid];
  }
  g_ctx[b * ENCD + tid] = a0 * invS;
  g_ctx[b * ENCD + 256 + tid] = a1 * invS;
}

// ---------------- projection + gate ----------------
// grid 64 (b), 128 threads. reads h2_new = g_h2[1-pp]
__global__ __launch_bounds__(128) void k_proj(
    int pp, const float* __restrict__ projW, const float* __restrict__ gateW,
    const float* __restrict__ gateB, float* __restrict__ out_mel,
    float* __restrict__ out_gate, int t_step) {
  const int b = blockIdx.x;
  const int tid = threadIdx.x;
  const float* __restrict__ h2 = g_h2[1 - pp];
  __shared__ float dh[RNN + ENCD];
  for (int i = tid; i < RNN; i += 128) dh[i] = h2[b * RNN + i];
  for (int i = tid; i < ENCD; i += 128) dh[RNN + i] = g_ctx[b * ENCD + i];
  __syncthreads();
  if (tid < MEL) {
    float s = 0.f;
    for (int k = 0; k < RNN + ENCD; ++k) s += dh[k] * projW[k * MEL + tid];
    out_mel[(size_t)b * (MEL * TDEC) + tid * TDEC + t_step] = s;
  } else if (tid == MEL) {
    float s = gateB[0];
    for (int k = 0; k < RNN + ENCD; ++k) s += dh[k] * gateW[k];
    out_gate[b * TDEC + t_step] = s;
  }
}

extern "C" void kernel_launch(void* const* d_in, const int* in_sizes, int n_in,
                              void* d_out, int out_size, void* d_ws, size_t ws_size,
                              hipStream_t stream) {
  const float* memory = (const float*)d_in[0];
  const int* mlen = (const int*)d_in[1];
  const float* DT = (const float*)d_in[2];
  const float* qW = (const float*)d_in[3];
  const float* memW = (const float*)d_in[4];
  const float* locW = (const float*)d_in[5];
  const float* convW = (const float*)d_in[6];
  const float* wW = (const float*)d_in[7];
  const float* wb = (const float*)d_in[8];
  const float* pW0 = (const float*)d_in[9];
  const float* pW1 = (const float*)d_in[10];
  const float* Wih1 = (const float*)d_in[11];
  const float* Whh1 = (const float*)d_in[12];
  const float* bih1 = (const float*)d_in[13];
  const float* bhh1 = (const float*)d_in[14];
  const float* Wih2 = (const float*)d_in[15];
  const float* Whh2 = (const float*)d_in[16];
  const float* bih2 = (const float*)d_in[17];
  const float* bhh2 = (const float*)d_in[18];
  const float* projW = (const float*)d_in[19];
  const float* gateW = (const float*)d_in[20];
  const float* gateB = (const float*)d_in[21];
  (void)in_sizes; (void)n_in; (void)out_size; (void)d_ws; (void)ws_size;

  float* out_mel = (float*)d_out;
  float* out_gate = out_mel + (size_t)BB * MEL * TDEC;
  float* out_al = out_gate + (size_t)BB * TDEC;

  k_init<<<512, 256, 0, stream>>>();
  k_prenet<<<64 * 75, 256, 0, stream>>>(DT, pW0, pW1);
  k_pm<<<64 * 64, 128, 0, stream>>>(memory, memW);

  for (int t = 0; t < TDEC; ++t) {
    int pp = t & 1;
    k_gates_lstm<1><<<256, 256, 0, stream>>>(t, pp, Wih1, Whh1, bih1, bhh1);
    k_energies<<<128, 256, 0, stream>>>(pp, qW, convW, locW, wW, wb, mlen);
    k_softmax_ctx<<<64, 256, 0, stream>>>(memory, out_al, t);
    k_gates_lstm<2><<<256, 256, 0, stream>>>(t, pp, Wih2, Whh2, bih2, bhh2);
    k_proj<<<64, 128, 0, stream>>>(pp, projW, gateW, gateB, out_mel, out_gate, t);
  }
}

// Round 5
// 139940.393 us; speedup vs baseline: 3.5024x; 3.5024x over previous
//
#include <hip/hip_runtime.h>
#include <hip/hip_bf16.h>

#define BB 64          // batch
#define TENC 512
#define ENCD 512
#define TDEC 600
#define MEL 80
#define RNN 1024
#define ATT 128
#define CC 32
#define KSZ 31
#define PADC 15
#define PRE 256

// ---- all scratch in __device__ globals: d_ws is NOT used at all ----
__device__ float g_dall[(size_t)TDEC * BB * PRE];   // prenet out, 39.3 MB
__device__ float g_pm[(size_t)BB * TENC * ATT];     // processed_memory, 16.8 MB
__device__ float g_part[8][BB][4096];               // split-K partials, 8 MB
__device__ float g_h1[2][BB * RNN];
__device__ float g_c1[BB * RNN];
__device__ float g_h2[2][BB * RNN];
__device__ float g_c2[BB * RNN];
__device__ float g_ctx[BB * ENCD];
__device__ float g_cum[BB * TENC];
__device__ float g_ebuf[BB * TENC];

__device__ __forceinline__ float fast_tanh(float x) {
  x = fminf(15.f, fmaxf(-15.f, x));
  float e = __expf(2.f * x);
  return __fdividef(e - 1.f, e + 1.f);
}
__device__ __forceinline__ float fast_sig(float x) {
  x = fminf(30.f, fmaxf(-30.f, x));
  return __fdividef(1.f, 1.f + __expf(-x));
}

// ---------------- init: zero recurrent state (every call) ----------------
__global__ __launch_bounds__(256) void k_init() {
  int i = blockIdx.x * 256 + threadIdx.x;   // grid 512 -> i < 131072
  if (i < 2 * BB * RNN) {
    ((float*)g_h1)[i] = 0.f;
    ((float*)g_h2)[i] = 0.f;
  }
  if (i < BB * RNN) {
    g_c1[i] = 0.f;
    g_c2[i] = 0.f;
  }
  if (i < BB * ENCD) g_ctx[i] = 0.f;
  if (i < BB * TENC) g_cum[i] = 0.f;
}

// ---------------- prenet (all 600 steps, once) ----------------
__global__ __launch_bounds__(256) void k_prenet(
    const float* __restrict__ DT, const float* __restrict__ W0,
    const float* __restrict__ W1) {
  int bid = blockIdx.x;
  int b = bid / 75, ch = bid % 75, t0 = ch * 8;
  int tid = threadIdx.x;
  __shared__ float xl[8 * 80];
  __shared__ float hl[8 * 256];
  for (int i = tid; i < 8 * 80; i += 256) {
    int tt = i / 80, m = i % 80, t = t0 + tt;
    xl[i] = (t == 0) ? 0.f : DT[(size_t)b * (MEL * TDEC) + m * TDEC + (t - 1)];
  }
  __syncthreads();
  {
    float acc[8] = {0, 0, 0, 0, 0, 0, 0, 0};
    for (int m = 0; m < 80; ++m) {
      float w = W0[m * 256 + tid];
#pragma unroll
      for (int tt = 0; tt < 8; ++tt) acc[tt] += xl[tt * 80 + m] * w;
    }
#pragma unroll
    for (int tt = 0; tt < 8; ++tt) hl[tt * 256 + tid] = fmaxf(acc[tt], 0.f);
  }
  __syncthreads();
  {
    float acc[8] = {0, 0, 0, 0, 0, 0, 0, 0};
    for (int j = 0; j < 256; ++j) {
      float w = W1[j * 256 + tid];
#pragma unroll
      for (int tt = 0; tt < 8; ++tt) acc[tt] += hl[tt * 256 + j] * w;
    }
#pragma unroll
    for (int tt = 0; tt < 8; ++tt)
      g_dall[((size_t)(t0 + tt) * BB + b) * 256 + tid] = fmaxf(acc[tt], 0.f);
  }
}

// ---------------- processed_memory (once) ----------------
__global__ __launch_bounds__(128) void k_pm(
    const float* __restrict__ mem, const float* __restrict__ mW) {
  int bid = blockIdx.x;
  int b = bid >> 6, ch = bid & 63, t0 = ch * 8;
  int tid = threadIdx.x;
  __shared__ float ml[8 * 512];
  for (int i = tid; i < 8 * 512; i += 128) {
    int tt = i >> 9, d = i & 511;
    ml[i] = mem[((size_t)b * TENC + t0 + tt) * ENCD + d];
  }
  __syncthreads();
  float acc[8] = {0, 0, 0, 0, 0, 0, 0, 0};
  for (int d = 0; d < 512; ++d) {
    float w = mW[d * 128 + tid];
#pragma unroll
    for (int tt = 0; tt < 8; ++tt) acc[tt] += ml[tt * 512 + d] * w;
  }
#pragma unroll
  for (int tt = 0; tt < 8; ++tt)
    g_pm[((size_t)b * TENC + t0 + tt) * 128 + tid] = acc[tt];
}

// ---------------- split-K register-tiled gates GEMM ----------------
// PHASE 1: A = [dall_t(256) | ctx(512) | h1_prev(1024)], K=1792, W = Wih1/Whh1
// PHASE 2: A = [h1_new(1024) | ctx(512) | h2_prev(1024)], K=2560, W = Wih2/Whh2
// grid 512 = 64 col-tiles x 8 K-slices; 256 threads; thread = 4x4 micro-tile.
// writes g_part[ks][b][n].
template <int PHASE>
__global__ __launch_bounds__(256) void k_gemm(
    int t, int pp, const float* __restrict__ Wih, const float* __restrict__ Whh) {
  constexpr int K = (PHASE == 1) ? 1792 : 2560;
  constexpr int KSLICE = K / 8;                 // 224 / 320
  constexpr int KBLK = (PHASE == 1) ? 32 : 64;  // 7 / 5 blocks
  constexpr int Kih = (PHASE == 1) ? 768 : 1536;
  __shared__ float Al[KBLK][68];
  __shared__ float Wl[KBLK][68];
  const int tid = threadIdx.x;
  const int nt = blockIdx.x & 63;
  const int ks = blockIdx.x >> 6;
  const int n0 = nt * 64;
  const int k0 = ks * KSLICE;
  const int rowq = tid & 15;
  const int colq = tid >> 4;
  const int hn = 1 - pp;
  const float* __restrict__ h1p = g_h1[pp];
  const float* __restrict__ h1n = g_h1[hn];
  const float* __restrict__ h2p = g_h2[pp];
  float acc[4][4] = {{0.f}};
  for (int kb = 0; kb < KSLICE; kb += KBLK) {
    // stage A slice (KBLK x 64 batches), transposed: Al[kk][b]
#pragma unroll
    for (int i = 0; i < KBLK * 64 / 256; ++i) {
      int e = i * 256 + tid;
      int kk = e & (KBLK - 1);
      int bb = e / KBLK;
      int kg = k0 + kb + kk;
      float v;
      if (PHASE == 1) {
        if (kg < 256)
          v = g_dall[(size_t)t * BB * PRE + bb * PRE + kg];
        else if (kg < 768)
          v = g_ctx[bb * ENCD + (kg - 256)];
        else
          v = h1p[bb * RNN + (kg - 768)];
      } else {
        if (kg < 1024)
          v = h1n[bb * RNN + kg];
        else if (kg < 1536)
          v = g_ctx[bb * ENCD + (kg - 1024)];
        else
          v = h2p[bb * RNN + (kg - 1536)];
      }
      Al[kk][bb] = v;
    }
    // stage W slice (KBLK x 64 cols) via float4, coalesced rows
#pragma unroll
    for (int i = 0; i < KBLK * 16 / 256; ++i) {
      int e = i * 256 + tid;
      int c4 = e & 15, kk = e >> 4;
      int kg = k0 + kb + kk;
      const float* src = (kg < Kih)
                             ? (Wih + (size_t)kg * 4096 + n0 + c4 * 4)
                             : (Whh + (size_t)(kg - Kih) * 4096 + n0 + c4 * 4);
      float4 w = *(const float4*)src;
      *(float4*)&Wl[kk][c4 * 4] = w;
    }
    __syncthreads();
#pragma unroll 8
    for (int kk = 0; kk < KBLK; ++kk) {
      float4 a4 = *(float4*)&Al[kk][rowq * 4];
      float4 w4 = *(float4*)&Wl[kk][colq * 4];
      float av[4] = {a4.x, a4.y, a4.z, a4.w};
      float wv[4] = {w4.x, w4.y, w4.z, w4.w};
#pragma unroll
      for (int ii = 0; ii < 4; ++ii)
#pragma unroll
        for (int jj = 0; jj < 4; ++jj) acc[ii][jj] += av[ii] * wv[jj];
    }
    __syncthreads();
  }
#pragma unroll
  for (int ii = 0; ii < 4; ++ii) {
    float4 o = {acc[ii][0], acc[ii][1], acc[ii][2], acc[ii][3]};
    *(float4*)&g_part[ks][4 * rowq + ii][n0 + colq * 4] = o;
  }
}

// ---------------- split-K reduce + LSTM pointwise ----------------
// grid 256, 256 threads: idx = b*1024 + hcol
template <int PHASE>
__global__ __launch_bounds__(256) void k_reduce_lstm(
    int pp, const float* __restrict__ bih, const float* __restrict__ bhh) {
  const int idx = blockIdx.x * 256 + threadIdx.x;
  const int b = idx >> 10;
  const int hcol = idx & 1023;
  float gi = 0.f, gf = 0.f, gg = 0.f, go = 0.f;
#pragma unroll
  for (int ks = 0; ks < 8; ++ks) {
    const float* p = &g_part[ks][b][0];
    gi += p[hcol];
    gf += p[1024 + hcol];
    gg += p[2048 + hcol];
    go += p[3072 + hcol];
  }
  gi += bih[hcol] + bhh[hcol];
  gf += bih[1024 + hcol] + bhh[1024 + hcol];
  gg += bih[2048 + hcol] + bhh[2048 + hcol];
  go += bih[3072 + hcol] + bhh[3072 + hcol];
  float* __restrict__ c_st = (PHASE == 1) ? g_c1 : g_c2;
  float* __restrict__ h_out = (PHASE == 1) ? g_h1[1 - pp] : g_h2[1 - pp];
  float c_old = c_st[idx];
  float cn = fast_sig(gf) * c_old + fast_sig(gi) * fast_tanh(gg);
  c_st[idx] = cn;
  h_out[idx] = fast_sig(go) * fast_tanh(cn);
}

// ---------------- attention energies ----------------
// grid 128 (b*2 halves), 256 threads (one t each). reads h1_new = g_h1[1-pp]
__global__ __launch_bounds__(256) void k_energies(
    int pp, const float* __restrict__ qW, const float* __restrict__ convW,
    const float* __restrict__ locW, const float* __restrict__ wW,
    const float* __restrict__ wb, const int* __restrict__ mlen) {
  const int b = blockIdx.x >> 1;
  const int t0 = (blockIdx.x & 1) * 256;
  const int tid = threadIdx.x;
  const float* __restrict__ h1 = g_h1[1 - pp];
  __shared__ float cumext[TENC + 2 * PADC];
  __shared__ float h1l[RNN];
  __shared__ float pql[ATT];
  __shared__ float cWl[CC * KSZ];
  __shared__ float lWl[CC * ATT];
  __shared__ float wl[ATT];
  for (int i = tid; i < TENC; i += 256) cumext[PADC + i] = g_cum[b * TENC + i];
  if (tid < PADC) { cumext[tid] = 0.f; cumext[TENC + PADC + tid] = 0.f; }
  for (int i = tid; i < RNN; i += 256) h1l[i] = h1[b * RNN + i];
  for (int i = tid; i < CC * KSZ; i += 256) cWl[i] = convW[i];
  for (int i = tid; i < CC * ATT; i += 256) lWl[i] = locW[i];
  if (tid < ATT) wl[tid] = wW[tid];
  __syncthreads();
  if (tid < ATT) {
    float s = 0.f;
    for (int k = 0; k < RNN; ++k) s += h1l[k] * qW[k * ATT + tid];
    pql[tid] = s;
  }
  __syncthreads();
  const int t = t0 + tid;
  float win[KSZ];
#pragma unroll
  for (int k = 0; k < KSZ; ++k) win[k] = cumext[t0 + tid + k];
  float lc[CC];
#pragma unroll
  for (int c = 0; c < CC; ++c) {
    float s = 0.f;
#pragma unroll
    for (int k = 0; k < KSZ; ++k) s += win[k] * cWl[c * KSZ + k];
    lc[c] = s;
  }
  const float* pmrow = g_pm + ((size_t)b * TENC + t) * ATT;
  float e = 0.f;
  for (int a = 0; a < ATT; ++a) {
    float v = pql[a] + pmrow[a];
#pragma unroll
    for (int c = 0; c < CC; ++c) v += lc[c] * lWl[c * ATT + a];
    e += wl[a] * fast_tanh(v);
  }
  int len = mlen[b];
  g_ebuf[b * TENC + t] = (t >= len) ? -1e9f : (e + wb[0]);
}

// ---------------- softmax + ctx + cum + alignment out ----------------
// grid 128 (b*2 D-halves), 256 threads
__global__ __launch_bounds__(256) void k_softmax_ctx(
    const float* __restrict__ memory, float* __restrict__ out_al, int t_step) {
  const int b = blockIdx.x >> 1;
  const int half = blockIdx.x & 1;
  const int tid = threadIdx.x;
  __shared__ float pl[TENC];
  __shared__ float rmax[4], rsum[4];
  float e0 = g_ebuf[b * TENC + tid], e1 = g_ebuf[b * TENC + 256 + tid];
  float m = fmaxf(e0, e1);
#pragma unroll
  for (int o = 32; o > 0; o >>= 1) m = fmaxf(m, __shfl_xor(m, o, 64));
  if ((tid & 63) == 0) rmax[tid >> 6] = m;
  __syncthreads();
  float M = fmaxf(fmaxf(rmax[0], rmax[1]), fmaxf(rmax[2], rmax[3]));
  float p0 = __expf(e0 - M), p1 = __expf(e1 - M);
  pl[tid] = p0;
  pl[tid + 256] = p1;
  float s = p0 + p1;
#pragma unroll
  for (int o = 32; o > 0; o >>= 1) s += __shfl_xor(s, o, 64);
  if ((tid & 63) == 0) rsum[tid >> 6] = s;
  __syncthreads();
  float S = rsum[0] + rsum[1] + rsum[2] + rsum[3];
  float invS = __fdividef(1.f, S);
  {
    int i = half * 256 + tid;
    float av = pl[i] * invS;
    out_al[(size_t)b * (TDEC * TENC) + (size_t)t_step * TENC + i] = av;
    g_cum[b * TENC + i] += av;
  }
  const int d = half * 256 + tid;
  float a0 = 0.f;
  const float* mb = memory + (size_t)b * TENC * ENCD;
  for (int tt = 0; tt < TENC; ++tt) a0 += pl[tt] * mb[(size_t)tt * ENCD + d];
  g_ctx[b * ENCD + d] = a0 * invS;
}

// ---------------- projection + gate ----------------
// grid 64 (b), 128 threads. reads h2_new = g_h2[1-pp]
__global__ __launch_bounds__(128) void k_proj(
    int pp, const float* __restrict__ projW, const float* __restrict__ gateW,
    const float* __restrict__ gateB, float* __restrict__ out_mel,
    float* __restrict__ out_gate, int t_step) {
  const int b = blockIdx.x;
  const int tid = threadIdx.x;
  const float* __restrict__ h2 = g_h2[1 - pp];
  __shared__ float dh[RNN + ENCD];
  for (int i = tid; i < RNN; i += 128) dh[i] = h2[b * RNN + i];
  for (int i = tid; i < ENCD; i += 128) dh[RNN + i] = g_ctx[b * ENCD + i];
  __syncthreads();
  if (tid < MEL) {
    float s = 0.f;
    for (int k = 0; k < RNN + ENCD; ++k) s += dh[k] * projW[k * MEL + tid];
    out_mel[(size_t)b * (MEL * TDEC) + tid * TDEC + t_step] = s;
  } else if (tid == MEL) {
    float s = gateB[0];
    for (int k = 0; k < RNN + ENCD; ++k) s += dh[k] * gateW[k];
    out_gate[b * TDEC + t_step] = s;
  }
}

extern "C" void kernel_launch(void* const* d_in, const int* in_sizes, int n_in,
                              void* d_out, int out_size, void* d_ws, size_t ws_size,
                              hipStream_t stream) {
  const float* memory = (const float*)d_in[0];
  const int* mlen = (const int*)d_in[1];
  const float* DT = (const float*)d_in[2];
  const float* qW = (const float*)d_in[3];
  const float* memW = (const float*)d_in[4];
  const float* locW = (const float*)d_in[5];
  const float* convW = (const float*)d_in[6];
  const float* wW = (const float*)d_in[7];
  const float* wb = (const float*)d_in[8];
  const float* pW0 = (const float*)d_in[9];
  const float* pW1 = (const float*)d_in[10];
  const float* Wih1 = (const float*)d_in[11];
  const float* Whh1 = (const float*)d_in[12];
  const float* bih1 = (const float*)d_in[13];
  const float* bhh1 = (const float*)d_in[14];
  const float* Wih2 = (const float*)d_in[15];
  const float* Whh2 = (const float*)d_in[16];
  const float* bih2 = (const float*)d_in[17];
  const float* bhh2 = (const float*)d_in[18];
  const float* projW = (const float*)d_in[19];
  const float* gateW = (const float*)d_in[20];
  const float* gateB = (const float*)d_in[21];
  (void)in_sizes; (void)n_in; (void)out_size; (void)d_ws; (void)ws_size;

  float* out_mel = (float*)d_out;
  float* out_gate = out_mel + (size_t)BB * MEL * TDEC;
  float* out_al = out_gate + (size_t)BB * TDEC;

  k_init<<<512, 256, 0, stream>>>();
  k_prenet<<<64 * 75, 256, 0, stream>>>(DT, pW0, pW1);
  k_pm<<<64 * 64, 128, 0, stream>>>(memory, memW);

  for (int t = 0; t < TDEC; ++t) {
    int pp = t & 1;
    k_gemm<1><<<512, 256, 0, stream>>>(t, pp, Wih1, Whh1);
    k_reduce_lstm<1><<<256, 256, 0, stream>>>(pp, bih1, bhh1);
    k_energies<<<128, 256, 0, stream>>>(pp, qW, convW, locW, wW, wb, mlen);
    k_softmax_ctx<<<128, 256, 0, stream>>>(memory, out_al, t);
    k_gemm<2><<<512, 256, 0, stream>>>(t, pp, Wih2, Whh2);
    k_reduce_lstm<2><<<256, 256, 0, stream>>>(pp, bih2, bhh2);
    k_proj<<<64, 128, 0, stream>>>(pp, projW, gateW, gateB, out_mel, out_gate, t);
  }
}